// Round 6
// baseline (956.725 us; speedup 1.0000x reference)
//
#include <hip/hip_runtime.h>
#include <hip/hip_bf16.h>
#include <stdint.h>
#include <stddef.h>

#define BB 2
#define NN 384
#define DD 768
#define HH 256
#define SS 64
#define NHH 8
#define DHH 96

typedef __attribute__((ext_vector_type(8))) short bf16x8;
typedef __attribute__((ext_vector_type(4))) float f32x4;

__device__ __forceinline__ float bits_f(unsigned short u){
  unsigned x = ((unsigned)u) << 16; float f; __builtin_memcpy(&f, &x, 4); return f;
}
__device__ __forceinline__ unsigned short f_bits(float a){
  unsigned x; __builtin_memcpy(&x, &a, 4);
  unsigned r = x + 0x7fffu + ((x >> 16) & 1u);
  return (unsigned short)(r >> 16);
}
__device__ __forceinline__ float lo_f(unsigned u){ unsigned x = u << 16; float f; __builtin_memcpy(&f,&x,4); return f; }
__device__ __forceinline__ float hi_f(unsigned u){ unsigned x = u & 0xffff0000u; float f; __builtin_memcpy(&f,&x,4); return f; }

// ---------------- prep: w2T transpose->bf16, w1t bf16 [256c][32k] (K padded), zero geo_acc ----------------
__global__ void k_prep(const float* __restrict__ w2, short* __restrict__ w2T,
                       float* __restrict__ ga, const float* __restrict__ w1g,
                       short* __restrict__ w1t){
  int idx = blockIdx.x * 256 + threadIdx.x;           // 0 .. 196607
  int d = idx >> 8, k = idx & 255;
  w2T[idx] = (short)f_bits(w2[k * DD + d]);
  ga[idx] = 0.f; ga[idx + 196608] = 0.f; ga[idx + 393216] = 0.f;
  if (idx < 8192){
    int c = idx >> 5, kk = idx & 31;
    w1t[idx] = (kk < 9) ? (short)f_bits(w1g[kk*256 + c]) : (short)0;
  }
}

// ---------------- fused geometric encoder; WG = (b,i,jt), 64 j-rows, 512 thr ----------------
__global__ __launch_bounds__(512) void k_geo(
    const float* __restrict__ coord,
    const short* __restrict__ w1t,
    const float* __restrict__ b1g, const float* __restrict__ g1g,
    const float* __restrict__ be1g,
    const float* __restrict__ b2g, const float* __restrict__ g2g,
    const short* __restrict__ w2T, float* __restrict__ geo_acc)
{
  __shared__ short relbf[64*32];   // bf16 rel rows, K padded to 32
  __shared__ short h_bf[64*256];   // chunk-swizzled: phys_chunk=(cc+row)&31
  __shared__ float rsum[64], rssq[64], rmean[64], rrstd[64];

  const int tid = threadIdx.x;
  const int pair = blockIdx.x % 768;
  const int jt   = blockIdx.x / 768;
  const int j0 = jt * 64;
  const int b = pair / NN;

  if (tid < 64){
    int j = j0 + tid;
    float cix = coord[pair*3+0], ciy = coord[pair*3+1], ciz = coord[pair*3+2];
    float dx = cix - coord[(b*NN+j)*3+0];
    float dy = ciy - coord[(b*NN+j)*3+1];
    float dz = ciz - coord[(b*NN+j)*3+2];
    float dist = sqrtf(dx*dx + dy*dy + dz*dz);
    float inv = 1.f / fmaxf(dist, 1e-12f);
    float x = dx*inv, y = dy*inv, z = dz*inv;
    short* rr = &relbf[tid*32];
    rr[0]=(short)f_bits(dist); rr[1]=(short)f_bits(x);
    rr[2]=(short)f_bits(y);    rr[3]=(short)f_bits(z);
    rr[4]=0; rr[5]=0;
    rr[6]=(short)f_bits(y*z);  rr[7]=(short)f_bits(x*y); rr[8]=(short)f_bits(x*z);
    #pragma unroll
    for (int k=9;k<32;++k) rr[k]=0;
  } else if (tid < 192){
    int t = tid & 63; rsum[t]=0.f; rssq[t]=0.f;
  }
  __syncthreads();

  const int wave = tid >> 6, lane = tid & 63, quad = lane >> 4, l16 = lane & 15;

  // ---- phase 2: h = ReLU(LN(rel@w1+b1)) via MFMA; wave owns col-tiles {2w,2w+1}
  {
    bf16x8 af[4];
    #pragma unroll
    for (int rb=0;rb<4;++rb)
      af[rb] = *(const bf16x8*)&relbf[(rb*16 + l16)*32 + quad*8];
    f32x4 hacc[2][4];
    #pragma unroll
    for (int ci=0;ci<2;++ci){
      int cb = wave*2 + ci;
      bf16x8 bf = *(const bf16x8*)&w1t[(cb*16 + l16)*32 + quad*8];
      #pragma unroll
      for (int rb=0;rb<4;++rb)
        hacc[ci][rb] = __builtin_amdgcn_mfma_f32_16x16x32_bf16(af[rb], bf, (f32x4){0.f,0.f,0.f,0.f}, 0,0,0);
    }
    #pragma unroll
    for (int ci=0;ci<2;++ci){
      float bb = b1g[(wave*2+ci)*16 + l16];
      #pragma unroll
      for (int rb=0;rb<4;++rb){
        hacc[ci][rb][0]+=bb; hacc[ci][rb][1]+=bb; hacc[ci][rb][2]+=bb; hacc[ci][rb][3]+=bb;
      }
    }
    // per-row stats over this wave's 32 cols, then LDS atomics
    #pragma unroll
    for (int rb=0;rb<4;++rb){
      #pragma unroll
      for (int r=0;r<4;++r){
        float a0 = hacc[0][rb][r], a1 = hacc[1][rb][r];
        float s = a0 + a1, q = a0*a0 + a1*a1;
        s += __shfl_xor(s,1); q += __shfl_xor(q,1);
        s += __shfl_xor(s,2); q += __shfl_xor(q,2);
        s += __shfl_xor(s,4); q += __shfl_xor(q,4);
        s += __shfl_xor(s,8); q += __shfl_xor(q,8);
        if (l16 == 0){
          atomicAdd(&rsum[rb*16 + quad*4 + r], s);
          atomicAdd(&rssq[rb*16 + quad*4 + r], q);
        }
      }
    }
    __syncthreads();
    if (tid < 64){
      float m = rsum[tid]*(1.f/256.f);
      float v = rssq[tid]*(1.f/256.f) - m*m;
      rmean[tid] = m; rrstd[tid] = rsqrtf(v + 1e-5f);
      rsum[tid] = 0.f; rssq[tid] = 0.f;      // re-zero for phase-3 stats
    }
    __syncthreads();
    #pragma unroll
    for (int ci=0;ci<2;++ci){
      int cb = wave*2 + ci;
      int col = cb*16 + l16;
      float gg = g1g[col], bb = be1g[col];
      int cc = cb*2 + (l16>>3);
      #pragma unroll
      for (int rb=0;rb<4;++rb){
        #pragma unroll
        for (int r=0;r<4;++r){
          int row = rb*16 + quad*4 + r;
          float hn = (hacc[ci][rb][r]-rmean[row])*rrstd[row]*gg + bb;
          h_bf[row*256 + ((cc + row)&31)*8 + (l16&7)] = (short)f_bits(fmaxf(hn, 0.f));
        }
      }
    }
  }
  __syncthreads();

  // ---- phase 3: mm2 (256->768) via MFMA; wave owns 96 cols x 64 rows
  const int colbase = wave * 96 + l16;
  f32x4 acc[4][6];
  #pragma unroll
  for (int rb=0;rb<4;++rb)
    #pragma unroll
    for (int cb=0;cb<6;++cb) acc[rb][cb] = (f32x4){0.f,0.f,0.f,0.f};
  for (int ks=0;ks<8;++ks){
    bf16x8 af[4];
    #pragma unroll
    for (int rb=0;rb<4;++rb){
      int row = rb*16 + l16;
      af[rb] = *(const bf16x8*)&h_bf[row*256 + (((ks*4 + quad) + row)&31)*8];
    }
    bf16x8 bfv[6];
    #pragma unroll
    for (int cb=0;cb<6;++cb)
      bfv[cb] = *(const bf16x8*)&w2T[(size_t)(colbase + cb*16)*256 + ks*32 + quad*8];
    #pragma unroll
    for (int rb=0;rb<4;++rb)
      #pragma unroll
      for (int cb=0;cb<6;++cb)
        acc[rb][cb] = __builtin_amdgcn_mfma_f32_16x16x32_bf16(af[rb], bfv[cb], acc[rb][cb], 0,0,0);
  }
  #pragma unroll
  for (int cb=0;cb<6;++cb){
    float bb = b2g[colbase + cb*16];
    #pragma unroll
    for (int rb=0;rb<4;++rb){
      acc[rb][cb][0]+=bb; acc[rb][cb][1]+=bb; acc[rb][cb][2]+=bb; acc[rb][cb][3]+=bb;
    }
  }
  #pragma unroll
  for (int rb=0;rb<4;++rb){
    #pragma unroll
    for (int r=0;r<4;++r){
      float s = 0.f, q = 0.f;
      #pragma unroll
      for (int cb=0;cb<6;++cb){ float v = acc[rb][cb][r]; s += v; q += v*v; }
      s += __shfl_xor(s,1); q += __shfl_xor(q,1);
      s += __shfl_xor(s,2); q += __shfl_xor(q,2);
      s += __shfl_xor(s,4); q += __shfl_xor(q,4);
      s += __shfl_xor(s,8); q += __shfl_xor(q,8);
      if (l16 == 0){
        atomicAdd(&rsum[rb*16 + quad*4 + r], s);
        atomicAdd(&rssq[rb*16 + quad*4 + r], q);
      }
    }
  }
  __syncthreads();
  if (tid < 64){
    float m = rsum[tid]*(1.f/768.f);
    float v = rssq[tid]*(1.f/768.f) - m*m;
    rmean[tid] = m; rrstd[tid] = rsqrtf(v + 1e-5f);
  }
  __syncthreads();
  // ---- phase 4: normalize, scale by g2, column-sum over 64 rows -> global atomics
  {
    float mm_[4][4], rr_[4][4];
    #pragma unroll
    for (int rb=0;rb<4;++rb)
      #pragma unroll
      for (int r=0;r<4;++r){ int row = rb*16 + quad*4 + r; mm_[rb][r]=rmean[row]; rr_[rb][r]=rrstd[row]; }
    float* gp = geo_acc + (size_t)pair * DD;
    #pragma unroll
    for (int cb=0;cb<6;++cb){
      int col = colbase + cb*16;
      float cs = 0.f;
      #pragma unroll
      for (int rb=0;rb<4;++rb)
        #pragma unroll
        for (int r=0;r<4;++r) cs += (acc[rb][cb][r]-mm_[rb][r])*rr_[rb][r];
      cs *= g2g[col];
      cs += __shfl_xor(cs,16);
      cs += __shfl_xor(cs,32);
      if (quad == 0) atomicAdd(&gp[col], cs);
    }
  }
}

// ---------------- finalize geo: /384 + be2, write bf16 ----------------
__global__ void k_geofin(const float* __restrict__ ga, const float* __restrict__ be2g,
                         unsigned short* __restrict__ geo){
  int idx4 = blockIdx.x * 256 + threadIdx.x;      // 0..147455
  float4 v = ((const float4*)ga)[idx4];
  int base = idx4 * 4;
  int col = base % DD;
  geo[base+0] = f_bits(v.x*(1.f/384.f) + be2g[col+0]);
  geo[base+1] = f_bits(v.y*(1.f/384.f) + be2g[col+1]);
  geo[base+2] = f_bits(v.z*(1.f/384.f) + be2g[col+2]);
  geo[base+3] = f_bits(v.w*(1.f/384.f) + be2g[col+3]);
}

// ---------------- per-superpoint scatter mean ----------------
__global__ __launch_bounds__(256) void k_scatter(
    const int* __restrict__ lab, const float* __restrict__ feat,
    const unsigned short* __restrict__ geo,
    float* __restrict__ meanf, float* __restrict__ meang, float* __restrict__ cntw)
{
  __shared__ int ls[NN];
  __shared__ float sf[DD], sg[DD];
  __shared__ int cnt;
  const int tid = threadIdx.x;
  const int b = blockIdx.x / SS, s = blockIdx.x % SS;
  for (int n = tid; n < NN; n += 256) ls[n] = lab[b*NN + n];
  for (int c = tid; c < DD; c += 256){ sf[c]=0.f; sg[c]=0.f; }
  if (tid == 0) cnt = 0;
  __syncthreads();
  for (int n = 0; n < NN; ++n){
    if (ls[n] == s){
      if (tid == 0) ++cnt;
      const float* fr = feat + (size_t)(b*NN+n)*DD;
      const unsigned short* gr = geo + (size_t)(b*NN+n)*DD;
      for (int c = tid; c < DD; c += 256){ sf[c] += fr[c]; sg[c] += bits_f(gr[c]); }
    }
  }
  __syncthreads();
  float cf = (float)cnt;
  float denom = fmaxf(cf, 1.f);
  size_t base = (size_t)(b*SS+s)*DD;
  for (int c = tid; c < DD; c += 256){ meanf[base+c] = sf[c]/denom; meang[base+c] = sg[c]/denom; }
  if (tid == 0) cntw[b*SS+s] = cf;
}

// ---------------- aggregator MLP + combine with mean_g ----------------
__global__ __launch_bounds__(256) void k_agg(
    const float* __restrict__ meanf, const float* __restrict__ meang,
    const float* __restrict__ w1g, const float* __restrict__ b1g,
    const float* __restrict__ g1g, const float* __restrict__ be1g,
    const float* __restrict__ w2g, const float* __restrict__ b2g,
    const float* __restrict__ g2g, const float* __restrict__ be2g,
    float* __restrict__ comb)
{
  __shared__ float xr[DD];
  __shared__ float hr[HH];
  __shared__ float red[8];
  const int tid = threadIdx.x;
  const size_t base = (size_t)blockIdx.x * DD;
  for (int c = tid; c < DD; c += 256) xr[c] = meanf[base + c];
  __syncthreads();
  float a = b1g[tid];
  #pragma unroll 4
  for (int k = 0; k < DD; ++k) a += xr[k]*w1g[k*HH + tid];
  float s = a, q = a*a;
  for (int m = 32; m >= 1; m >>= 1){ s += __shfl_xor(s,m); q += __shfl_xor(q,m); }
  if ((tid & 63) == 0){ red[tid>>6] = s; red[4+(tid>>6)] = q; }
  __syncthreads();
  s = red[0]+red[1]+red[2]+red[3]; q = red[4]+red[5]+red[6]+red[7];
  float mean = s*(1.f/HH), var = q*(1.f/HH) - mean*mean, rstd = rsqrtf(var + 1e-5f);
  float h = fmaxf((a-mean)*rstd*g1g[tid] + be1g[tid], 0.f);
  hr[tid] = h;
  __syncthreads();
  float a2[3];
  #pragma unroll
  for (int u = 0; u < 3; ++u){
    int c = tid + 256*u;
    float t = b2g[c];
    #pragma unroll 4
    for (int k = 0; k < HH; ++k) t += hr[k]*w2g[k*DD + c];
    a2[u] = t;
  }
  float s2 = a2[0]+a2[1]+a2[2], q2 = a2[0]*a2[0]+a2[1]*a2[1]+a2[2]*a2[2];
  for (int m = 32; m >= 1; m >>= 1){ s2 += __shfl_xor(s2,m); q2 += __shfl_xor(q2,m); }
  __syncthreads();
  if ((tid & 63) == 0){ red[tid>>6] = s2; red[4+(tid>>6)] = q2; }
  __syncthreads();
  s2 = red[0]+red[1]+red[2]+red[3]; q2 = red[4]+red[5]+red[6]+red[7];
  float mean2 = s2*(1.f/DD), rstd2 = rsqrtf(q2*(1.f/DD) - mean2*mean2 + 1e-5f);
  #pragma unroll
  for (int u = 0; u < 3; ++u){
    int c = tid + 256*u;
    comb[base + c] = (a2[u]-mean2)*rstd2*g2g[c] + be2g[c] + meang[base + c];
  }
}

// ---------------- gather + enhanced (fp32 out) ----------------
__global__ void k_enhance(const float* __restrict__ feat, const int* __restrict__ lab,
                          const float* __restrict__ cntw, const float* __restrict__ comb,
                          float* __restrict__ enh)
{
  int idx = blockIdx.x * 256 + threadIdx.x;
  int c = idx % DD; int bn = idx / DD; int b = bn / NN;
  int l = lab[bn];
  float f = feat[idx];
  float cg = comb[(size_t)(b*SS + l)*DD + c];
  float cnt = cntw[b*SS + l];
  enh[idx] = (cnt >= 2.0f) ? (0.7f*f + 0.3f*cg) : f;
}

// ---------------- q/k/v projections (row GEMM, 8 rows per WG); q pre-scaled, bf16 out ----------------
__global__ __launch_bounds__(256) void k_qkv(
    const float* __restrict__ enh, const unsigned short* __restrict__ geo,
    const float* __restrict__ wq, const float* __restrict__ bq,
    const float* __restrict__ wk, const float* __restrict__ bk,
    const float* __restrict__ wv, const float* __restrict__ bv,
    unsigned short* __restrict__ qo, unsigned short* __restrict__ ko, unsigned short* __restrict__ vo)
{
  __shared__ float xs[8*DD];
  const int tid = threadIdx.x;
  const int m = blockIdx.x / 96, rb = blockIdx.x % 96;
  const float* W = (m == 0) ? wq : (m == 1 ? wk : wv);
  const float* Bv = (m == 0) ? bq : (m == 1 ? bk : bv);
  unsigned short* Y = (m == 0) ? qo : (m == 1 ? ko : vo);
  const float oscale = (m == 0) ? 0.10206207261596577f : 1.0f;   // q pre-scaled by 1/sqrt(96)
  const size_t r0 = (size_t)rb * 8;
  if (m == 0){
    for (int x = tid; x < 8*DD; x += 256) xs[x] = enh[r0*DD + x];
  } else {
    for (int x = tid; x < 8*DD; x += 256) xs[x] = bits_f(geo[r0*DD + x]);
  }
  __syncthreads();
  float acc[8][3];
  {
    float b0 = Bv[tid], b1 = Bv[tid+256], b2 = Bv[tid+512];
    #pragma unroll
    for (int r = 0; r < 8; ++r){ acc[r][0]=b0; acc[r][1]=b1; acc[r][2]=b2; }
  }
  #pragma unroll 4
  for (int k = 0; k < DD; ++k){
    float w0 = W[(size_t)k*DD + tid];
    float w1 = W[(size_t)k*DD + tid + 256];
    float w2 = W[(size_t)k*DD + tid + 512];
    #pragma unroll
    for (int r = 0; r < 8; ++r){
      float x = xs[r*DD + k];
      acc[r][0]+=x*w0; acc[r][1]+=x*w1; acc[r][2]+=x*w2;
    }
  }
  #pragma unroll
  for (int r = 0; r < 8; ++r){
    Y[(r0+r)*DD + tid]       = f_bits(acc[r][0]*oscale);
    Y[(r0+r)*DD + tid + 256] = f_bits(acc[r][1]*oscale);
    Y[(r0+r)*DD + tid + 512] = f_bits(acc[r][2]*oscale);
  }
}

// ---------------- attention: per (b, head, 32-q tile); bf16 K/V tiles in LDS ----------------
__global__ __launch_bounds__(256) void k_attn(
    const unsigned short* __restrict__ qws, const unsigned short* __restrict__ kws,
    const unsigned short* __restrict__ vws, unsigned short* __restrict__ ows)
{
  __shared__ short kt[64*104];
  __shared__ short vt[64*104];
  __shared__ float st[32*66];
  __shared__ float lsum[32];
  const int tid = threadIdx.x;
  const int blk = blockIdx.x;
  const int b = blk / (NHH*12); int rem = blk % (NHH*12);
  const int h = rem / 12; const int qt = rem % 12; const int q0 = qt*32;
  const int sq = tid >> 3, jp = tid & 7;        // score mapping
  const int qp = tid >> 4, dp = tid & 15;       // PV mapping
  unsigned qreg[48];
  {
    const unsigned* qr = (const unsigned*)(qws + (size_t)(b*NN + q0 + sq)*DD + h*DHH);
    #pragma unroll
    for (int d2 = 0; d2 < 48; ++d2) qreg[d2] = qr[d2];
  }
  if (tid < 32) lsum[tid] = 0.f;
  float Oacc[2][6];
  #pragma unroll
  for (int a = 0; a < 2; ++a)
    #pragma unroll
    for (int m = 0; m < 6; ++m) Oacc[a][m] = 0.f;

  for (int jt = 0; jt < 6; ++jt){
    const int j0 = jt * 64;
    __syncthreads();
    for (int x = tid; x < 64*48; x += 256){
      int jl = x / 48, du = x % 48;
      size_t rowoff = (size_t)(b*NN + j0 + jl)*DD + h*DHH;
      ((unsigned*)&kt[jl*104])[du] = ((const unsigned*)(kws + rowoff))[du];
      ((unsigned*)&vt[jl*104])[du] = ((const unsigned*)(vws + rowoff))[du];
    }
    __syncthreads();
    float lpart = 0.f;
    #pragma unroll
    for (int jj = 0; jj < 8; ++jj){
      int j = jp*8 + jj;
      const uint4* kr4 = (const uint4*)&kt[j*104];
      float s = 0.f;
      #pragma unroll
      for (int d4 = 0; d4 < 12; ++d4){
        uint4 kk = kr4[d4];
        unsigned q0r = qreg[4*d4], q1r = qreg[4*d4+1], q2r = qreg[4*d4+2], q3r = qreg[4*d4+3];
        s += lo_f(kk.x)*lo_f(q0r) + hi_f(kk.x)*hi_f(q0r);
        s += lo_f(kk.y)*lo_f(q1r) + hi_f(kk.y)*hi_f(q1r);
        s += lo_f(kk.z)*lo_f(q2r) + hi_f(kk.z)*hi_f(q2r);
        s += lo_f(kk.w)*lo_f(q3r) + hi_f(kk.w)*hi_f(q3r);
      }
      float p = __expf(s);
      st[sq*66 + j] = p;
      lpart += p;
    }
    lpart += __shfl_xor(lpart,1);
    lpart += __shfl_xor(lpart,2);
    lpart += __shfl_xor(lpart,4);
    if (jp == 0) lsum[sq] += lpart;
    __syncthreads();
    #pragma unroll 4
    for (int j = 0; j < 64; ++j){
      float p0 = st[(2*qp)*66 + j];
      float p1 = st[(2*qp+1)*66 + j];
      const unsigned* vr = (const unsigned*)&vt[j*104 + dp*6];
      #pragma unroll
      for (int m = 0; m < 3; ++m){
        unsigned vv = vr[m];
        float v0 = lo_f(vv), v1 = hi_f(vv);
        Oacc[0][2*m]   += p0*v0; Oacc[0][2*m+1] += p0*v1;
        Oacc[1][2*m]   += p1*v0; Oacc[1][2*m+1] += p1*v1;
      }
    }
  }
  __syncthreads();
  float l0 = 1.f / lsum[2*qp], l1 = 1.f / lsum[2*qp+1];
  size_t ob = (size_t)(b*NN + q0)*DD + h*DHH + dp*6;
  #pragma unroll
  for (int m = 0; m < 6; ++m){
    ows[ob + (size_t)(2*qp)*DD + m]   = f_bits(Oacc[0][m]*l0);
    ows[ob + (size_t)(2*qp+1)*DD + m] = f_bits(Oacc[1][m]*l1);
  }
}

// ---------------- output projection + residual (8 rows per WG), write fp32 ----------------
__global__ __launch_bounds__(256) void k_out(
    const unsigned short* __restrict__ ows, const float* __restrict__ enh,
    const float* __restrict__ wo, const float* __restrict__ bo,
    float* __restrict__ out)
{
  __shared__ float xs[8*DD];
  const int tid = threadIdx.x;
  const size_t r0 = (size_t)blockIdx.x * 8;
  for (int x = tid; x < 8*DD; x += 256) xs[x] = bits_f(ows[r0*DD + x]);
  __syncthreads();
  float acc[8][3];
  {
    float b0 = bo[tid], b1 = bo[tid+256], b2 = bo[tid+512];
    #pragma unroll
    for (int r = 0; r < 8; ++r){ acc[r][0]=b0; acc[r][1]=b1; acc[r][2]=b2; }
  }
  #pragma unroll 4
  for (int k = 0; k < DD; ++k){
    float w0 = wo[(size_t)k*DD + tid];
    float w1 = wo[(size_t)k*DD + tid + 256];
    float w2 = wo[(size_t)k*DD + tid + 512];
    #pragma unroll
    for (int r = 0; r < 8; ++r){
      float x = xs[r*DD + k];
      acc[r][0]+=x*w0; acc[r][1]+=x*w1; acc[r][2]+=x*w2;
    }
  }
  #pragma unroll
  for (int r = 0; r < 8; ++r){
    #pragma unroll
    for (int u = 0; u < 3; ++u){
      size_t idx = (r0+r)*DD + tid + 256*u;
      out[idx] = enh[idx] + 0.5f*acc[r][u];
    }
  }
}

extern "C" void kernel_launch(void* const* d_in, const int* in_sizes, int n_in,
                              void* d_out, int out_size, void* d_ws, size_t ws_size,
                              hipStream_t stream) {
  const float* coord = (const float*)d_in[0];
  const float* feat  = (const float*)d_in[1];
  const int*   lab   = (const int*)d_in[2];
  const float* ge_w1 = (const float*)d_in[3];
  const float* ge_b1 = (const float*)d_in[4];
  const float* ge_g1 = (const float*)d_in[5];
  const float* ge_be1= (const float*)d_in[6];
  const float* ge_w2 = (const float*)d_in[7];
  const float* ge_b2 = (const float*)d_in[8];
  const float* ge_g2 = (const float*)d_in[9];
  const float* ge_be2= (const float*)d_in[10];
  const float* ag_w1 = (const float*)d_in[11];
  const float* ag_b1 = (const float*)d_in[12];
  const float* ag_g1 = (const float*)d_in[13];
  const float* ag_be1= (const float*)d_in[14];
  const float* ag_w2 = (const float*)d_in[15];
  const float* ag_b2 = (const float*)d_in[16];
  const float* ag_g2 = (const float*)d_in[17];
  const float* ag_be2= (const float*)d_in[18];
  const float* wq = (const float*)d_in[19];
  const float* bq = (const float*)d_in[20];
  const float* wk = (const float*)d_in[21];
  const float* bk = (const float*)d_in[22];
  const float* wv = (const float*)d_in[23];
  const float* bv = (const float*)d_in[24];
  const float* wo = (const float*)d_in[25];
  const float* bo = (const float*)d_in[26];

  // Workspace (8,258,048 B total, same as R5). Overlays:
  //  geo_acc (fp32) overlays qw+kw (dead until k_qkv);
  //  w2T overlays meanf (w2T dead after k_geo);
  //  w1t overlays comb (w1t dead after k_geo, comb written by k_agg later);
  //  ow overlays geo_bf (geo dead after k_qkv).
  char* w = (char*)d_ws;
  unsigned short* geo_bf = (unsigned short*)(w);             // 1,179,648 B  [also ow]
  float*          enh_f  = (float*)(w + 1179648);            // 2,359,296 B
  unsigned short* qw_bf  = (unsigned short*)(w + 3538944);   // 1,179,648 B  [geo_acc lo]
  unsigned short* kw_bf  = (unsigned short*)(w + 4718592);   // 1,179,648 B  [geo_acc hi]
  unsigned short* vw_bf  = (unsigned short*)(w + 5898240);   // 1,179,648 B
  short*          w2T    = (short*)(w + 7077888);            //   393,216 B  [also meanf]
  float*          meanf  = (float*)(w + 7077888);            //   393,216 B
  float*          meang  = (float*)(w + 7471104);            //   393,216 B
  float*          comb   = (float*)(w + 7864320);            //   393,216 B  [also w1t]
  short*          w1t    = (short*)(w + 7864320);            //    16,384 B overlay
  float*          cntw   = (float*)(w + 8257536);            //       512 B
  float*          geo_acc= (float*)(w + 3538944);            // 2,359,296 B overlay
  unsigned short* ow_bf  = geo_bf;

  hipLaunchKernelGGL(k_prep,    dim3(768),  dim3(256), 0, stream, ge_w2, w2T, geo_acc, ge_w1, w1t);
  hipLaunchKernelGGL(k_geo,     dim3(4608), dim3(512), 0, stream,
                     coord, w1t, ge_b1, ge_g1, ge_be1, ge_b2, ge_g2, w2T, geo_acc);
  hipLaunchKernelGGL(k_geofin,  dim3(576),  dim3(256), 0, stream, geo_acc, ge_be2, geo_bf);
  hipLaunchKernelGGL(k_scatter, dim3(128),  dim3(256), 0, stream,
                     lab, feat, geo_bf, meanf, meang, cntw);
  hipLaunchKernelGGL(k_agg,     dim3(128),  dim3(256), 0, stream,
                     meanf, meang, ag_w1, ag_b1, ag_g1, ag_be1, ag_w2, ag_b2, ag_g2, ag_be2, comb);
  hipLaunchKernelGGL(k_enhance, dim3(2304), dim3(256), 0, stream,
                     feat, lab, cntw, comb, enh_f);
  hipLaunchKernelGGL(k_qkv,     dim3(288),  dim3(256), 0, stream,
                     enh_f, geo_bf, wq, bq, wk, bk, wv, bv, qw_bf, kw_bf, vw_bf);
  hipLaunchKernelGGL(k_attn,    dim3(192),  dim3(256), 0, stream,
                     qw_bf, kw_bf, vw_bf, ow_bf);
  hipLaunchKernelGGL(k_out,     dim3(96),   dim3(256), 0, stream,
                     ow_bf, enh_f, wo, bo, (float*)d_out);
}

// Round 7
// 690.624 us; speedup vs baseline: 1.3853x; 1.3853x over previous
//
#include <hip/hip_runtime.h>
#include <hip/hip_bf16.h>
#include <stdint.h>
#include <stddef.h>

#define BB 2
#define NN 384
#define DD 768
#define HH 256
#define SS 64
#define NHH 8
#define DHH 96

typedef __attribute__((ext_vector_type(8))) short bf16x8;
typedef __attribute__((ext_vector_type(4))) float f32x4;

__device__ __forceinline__ float bits_f(unsigned short u){
  unsigned x = ((unsigned)u) << 16; float f; __builtin_memcpy(&f, &x, 4); return f;
}
__device__ __forceinline__ unsigned short f_bits(float a){
  unsigned x; __builtin_memcpy(&x, &a, 4);
  unsigned r = x + 0x7fffu + ((x >> 16) & 1u);
  return (unsigned short)(r >> 16);
}
__device__ __forceinline__ float lo_f(unsigned u){ unsigned x = u << 16; float f; __builtin_memcpy(&f,&x,4); return f; }
__device__ __forceinline__ float hi_f(unsigned u){ unsigned x = u & 0xffff0000u; float f; __builtin_memcpy(&f,&x,4); return f; }

// ---------------- prep: w2T/w1t bf16, zero gv, transpose wq/wk/wv/wo -> bf16 ----------------
__global__ void k_prep(const float* __restrict__ w2, short* __restrict__ w2T,
                       float* __restrict__ gv, const float* __restrict__ w1g,
                       short* __restrict__ w1t,
                       const float* __restrict__ wq, const float* __restrict__ wk,
                       const float* __restrict__ wv, const float* __restrict__ wo,
                       short* __restrict__ wqT, short* __restrict__ wkT,
                       short* __restrict__ wvT, short* __restrict__ woT){
  int idx = blockIdx.x * 256 + threadIdx.x;
  if (idx < 196608){
    int d = idx >> 8, k = idx & 255;
    w2T[idx] = (short)f_bits(w2[k * DD + d]);
    if (idx < 8192){
      int c = idx >> 5, kk = idx & 31;
      w1t[idx] = (kk < 9) ? (short)f_bits(w1g[kk*256 + c]) : (short)0;
    }
  } else if (idx < 396288){
    int t = idx - 196608;
    if (t < 199680) gv[t] = 0.f;
  } else {
    int t = idx - 396288;                 // 0 .. 2359295
    int mat = t / 589824, r = t % 589824;
    int n = r / 768, k = r % 768;
    const float* W = (mat==0)?wq:(mat==1)?wk:(mat==2)?wv:wo;
    short* T = (mat==0)?wqT:(mat==1)?wkT:(mat==2)?wvT:woT;
    T[r] = (short)f_bits(W[(size_t)k*768 + n]);
  }
}

// ---------------- Gram matrix G = W2 W2^T (bf16), s1, Wb, Sb, Sbb ----------------
__global__ __launch_bounds__(256) void k_gprep(const short* __restrict__ w2T,
                                               const float* __restrict__ b2,
                                               short* __restrict__ G, float* __restrict__ s1,
                                               float* __restrict__ wb, float* __restrict__ gscal){
  __shared__ float red[8];
  const int tid = threadIdx.x, blk = blockIdx.x;
  const unsigned short* wt = (const unsigned short*)w2T;
  if (blk < 256){
    float acc = 0.f;
    for (int c = 0; c < 768; ++c){
      float a = bits_f(wt[c*256 + blk]);     // broadcast
      float x = bits_f(wt[c*256 + tid]);     // coalesced
      acc += a * x;
    }
    G[blk*256 + tid] = (short)f_bits(acc);
  } else {
    float sa = 0.f, wa = 0.f;
    for (int c = 0; c < 768; ++c){
      float x = bits_f(wt[c*256 + tid]);
      float bb = b2[c];
      sa += x; wa += x * bb;
    }
    s1[tid] = sa; wb[tid] = wa;
    float pb = 0.f, pbb = 0.f;
    for (int c = tid; c < 768; c += 256){ float bb = b2[c]; pb += bb; pbb += bb*bb; }
    for (int m = 32; m >= 1; m >>= 1){ pb += __shfl_xor(pb,m); pbb += __shfl_xor(pbb,m); }
    if ((tid & 63) == 0){ red[tid>>6] = pb; red[4+(tid>>6)] = pbb; }
    __syncthreads();
    if (tid == 0){ gscal[0] = red[0]+red[1]+red[2]+red[3]; gscal[1] = red[4]+red[5]+red[6]+red[7]; }
  }
}

// ---------------- geometric encoder core; WG = (pair, jt); stats via Gram trick ----------------
__global__ __launch_bounds__(512, 4) void k_geo(
    const float* __restrict__ coord, const short* __restrict__ w1t,
    const float* __restrict__ b1g, const float* __restrict__ g1g, const float* __restrict__ be1g,
    const short* __restrict__ Gm, const float* __restrict__ s1g, const float* __restrict__ wbg,
    const float* __restrict__ gscal, float* __restrict__ gv)
{
  __shared__ short relbf[64*40];    // bf16 rel rows, stride 40 (bank-safe), k<32 used
  __shared__ short h_bf[64*256];    // chunk-swizzled: phys_chunk=((col>>3)+row)&31
  __shared__ float ssum[64], sssq[64];
  __shared__ float msum[64], wbsum[64], qsum[64];
  __shared__ float rmean[64], rrstd[64];

  const int tid = threadIdx.x;
  const int pair = blockIdx.x % 768;
  const int jt   = blockIdx.x / 768;
  const int j0 = jt * 64;
  const int b = pair / NN;

  if (tid < 64){
    int j = j0 + tid;
    float cix = coord[pair*3+0], ciy = coord[pair*3+1], ciz = coord[pair*3+2];
    float dx = cix - coord[(b*NN+j)*3+0];
    float dy = ciy - coord[(b*NN+j)*3+1];
    float dz = ciz - coord[(b*NN+j)*3+2];
    float dist = sqrtf(dx*dx + dy*dy + dz*dz);
    float inv = 1.f / fmaxf(dist, 1e-12f);
    float x = dx*inv, y = dy*inv, z = dz*inv;
    short* rr = &relbf[tid*40];
    rr[0]=(short)f_bits(dist); rr[1]=(short)f_bits(x);
    rr[2]=(short)f_bits(y);    rr[3]=(short)f_bits(z);
    rr[4]=0; rr[5]=0;
    rr[6]=(short)f_bits(y*z);  rr[7]=(short)f_bits(x*y); rr[8]=(short)f_bits(x*z);
    #pragma unroll
    for (int k=9;k<32;++k) rr[k]=0;
  } else if (tid < 128){
    ssum[tid-64]=0.f; sssq[tid-64]=0.f;
  } else if (tid < 192){
    msum[tid-128]=0.f; wbsum[tid-128]=0.f;
  } else if (tid < 256){
    qsum[tid-192]=0.f;
  }
  __syncthreads();

  const int wave = tid >> 6, lane = tid & 63, quad = lane >> 4, l16 = lane & 15;

  // ---- phase 2: H = ReLU(LN1(rel@w1+b1)); wave owns cols 32w..32w+31
  {
    bf16x8 af[4];
    #pragma unroll
    for (int rb=0;rb<4;++rb)
      af[rb] = *(const bf16x8*)&relbf[(rb*16 + l16)*40 + quad*8];
    f32x4 hacc[2][4];
    #pragma unroll
    for (int ci=0;ci<2;++ci){
      int cb = wave*2 + ci;
      bf16x8 bfw = *(const bf16x8*)&w1t[(cb*16 + l16)*32 + quad*8];
      #pragma unroll
      for (int rb=0;rb<4;++rb)
        hacc[ci][rb] = __builtin_amdgcn_mfma_f32_16x16x32_bf16(af[rb], bfw, (f32x4){0.f,0.f,0.f,0.f}, 0,0,0);
    }
    #pragma unroll
    for (int ci=0;ci<2;++ci){
      float bb = b1g[(wave*2+ci)*16 + l16];
      #pragma unroll
      for (int rb=0;rb<4;++rb){
        hacc[ci][rb][0]+=bb; hacc[ci][rb][1]+=bb; hacc[ci][rb][2]+=bb; hacc[ci][rb][3]+=bb;
      }
    }
    // LN1 row stats over 256 cols
    #pragma unroll
    for (int rb=0;rb<4;++rb){
      #pragma unroll
      for (int r=0;r<4;++r){
        float a0 = hacc[0][rb][r], a1 = hacc[1][rb][r];
        float s = a0 + a1, q = a0*a0 + a1*a1;
        s += __shfl_xor(s,1); q += __shfl_xor(q,1);
        s += __shfl_xor(s,2); q += __shfl_xor(q,2);
        s += __shfl_xor(s,4); q += __shfl_xor(q,4);
        s += __shfl_xor(s,8); q += __shfl_xor(q,8);
        if (l16 == 0){
          atomicAdd(&ssum[rb*16 + quad*4 + r], s);
          atomicAdd(&sssq[rb*16 + quad*4 + r], q);
        }
      }
    }
    __syncthreads();
    if (tid < 64){
      float m = ssum[tid]*(1.f/256.f);
      float v = sssq[tid]*(1.f/256.f) - m*m;
      rmean[tid] = m; rrstd[tid] = rsqrtf(v + 1e-5f);
    }
    __syncthreads();
    // normalize -> h (bf16, swizzled) + m/wb dot accumulation
    float g1c[2], be1c[2], s1c[2], wbc[2];
    #pragma unroll
    for (int ci=0;ci<2;++ci){
      int col = (wave*2+ci)*16 + l16;
      g1c[ci]=g1g[col]; be1c[ci]=be1g[col]; s1c[ci]=s1g[col]; wbc[ci]=wbg[col];
    }
    #pragma unroll
    for (int rb=0;rb<4;++rb){
      #pragma unroll
      for (int r=0;r<4;++r){
        int row = rb*16 + quad*4 + r;
        float mm = rmean[row], rs = rrstd[row];
        float pm = 0.f, pw = 0.f;
        #pragma unroll
        for (int ci=0;ci<2;++ci){
          int col = (wave*2+ci)*16 + l16;
          float hn = (hacc[ci][rb][r]-mm)*rs*g1c[ci] + be1c[ci];
          unsigned short hb = f_bits(fmaxf(hn, 0.f));
          h_bf[row*256 + (((col>>3)+row)&31)*8 + (col&7)] = (short)hb;
          float hv = bits_f(hb);
          pm += hv*s1c[ci]; pw += hv*wbc[ci];
        }
        pm += __shfl_xor(pm,1); pw += __shfl_xor(pw,1);
        pm += __shfl_xor(pm,2); pw += __shfl_xor(pw,2);
        pm += __shfl_xor(pm,4); pw += __shfl_xor(pw,4);
        pm += __shfl_xor(pm,8); pw += __shfl_xor(pw,8);
        if (l16 == 0){
          atomicAdd(&msum[row], pm);
          atomicAdd(&wbsum[row], pw);
        }
      }
    }
  }
  __syncthreads();

  // ---- phase 3: U = H@G (64x256), Q_j = sum_k U_jk h_jk; wave owns cols 32w..32w+31
  {
    f32x4 acc[4][2];
    #pragma unroll
    for (int rb=0;rb<4;++rb){ acc[rb][0]=(f32x4){0.f,0.f,0.f,0.f}; acc[rb][1]=(f32x4){0.f,0.f,0.f,0.f}; }
    for (int ks=0;ks<8;++ks){
      bf16x8 af[4];
      #pragma unroll
      for (int rb=0;rb<4;++rb){
        int row = rb*16 + l16;
        af[rb] = *(const bf16x8*)&h_bf[row*256 + (((ks*4 + quad) + row)&31)*8];
      }
      #pragma unroll
      for (int ci=0;ci<2;++ci){
        int n = (wave*2+ci)*16 + l16;
        bf16x8 bg = *(const bf16x8*)&Gm[n*256 + ks*32 + quad*8];
        #pragma unroll
        for (int rb=0;rb<4;++rb)
          acc[rb][ci] = __builtin_amdgcn_mfma_f32_16x16x32_bf16(af[rb], bg, acc[rb][ci], 0,0,0);
      }
    }
    #pragma unroll
    for (int rb=0;rb<4;++rb){
      #pragma unroll
      for (int r=0;r<4;++r){
        int row = rb*16 + quad*4 + r;
        float qp = 0.f;
        #pragma unroll
        for (int ci=0;ci<2;++ci){
          int col = (wave*2+ci)*16 + l16;
          float hv = bits_f((unsigned short)h_bf[row*256 + (((col>>3)+row)&31)*8 + (col&7)]);
          qp += acc[rb][ci][r] * hv;
        }
        qp += __shfl_xor(qp,1);
        qp += __shfl_xor(qp,2);
        qp += __shfl_xor(qp,4);
        qp += __shfl_xor(qp,8);
        if (l16 == 0) atomicAdd(&qsum[row], qp);
      }
    }
  }
  __syncthreads();
  // ---- LN2 stats per row from Gram identities
  if (tid < 64){
    float Sb = gscal[0], Sbb = gscal[1];
    float m2 = (msum[tid] + Sb)*(1.f/768.f);
    float ssq = qsum[tid] + 2.f*wbsum[tid] + Sbb;
    float var = ssq*(1.f/768.f) - m2*m2;
    rmean[tid] = m2; rrstd[tid] = rsqrtf(var + 1e-5f);
  }
  __syncthreads();
  // ---- phase 4: V += sum_j r_j h_j ; R += sum r_j ; T += sum m_j r_j
  if (tid < 64){
    float rr = rrstd[tid], tt = rmean[tid]*rrstd[tid];
    for (int m = 32; m >= 1; m >>= 1){ rr += __shfl_xor(rr,m); tt += __shfl_xor(tt,m); }
    if (tid == 0){
      atomicAdd(&gv[pair*260 + 256], rr);
      atomicAdd(&gv[pair*260 + 257], tt);
    }
  }
  if (tid < 256){
    float v = 0.f;
    int thi = tid >> 3, tlo = tid & 7;
    #pragma unroll 8
    for (int j = 0; j < 64; ++j){
      float hv = bits_f((unsigned short)h_bf[j*256 + ((thi + j)&31)*8 + tlo]);
      v += rrstd[j] * hv;
    }
    atomicAdd(&gv[pair*260 + tid], v);
  }
}

// ---------------- finalize geo: geo[col] = g2*(V.w2col + b2*R - T)/384 + be2 ----------------
__global__ __launch_bounds__(256) void k_geofin(
    const float* __restrict__ gv, const short* __restrict__ w2T,
    const float* __restrict__ b2g, const float* __restrict__ g2g,
    const float* __restrict__ be2g, unsigned short* __restrict__ geo){
  __shared__ float V[256];
  __shared__ float RT[2];
  const int tid = threadIdx.x, pair = blockIdx.x;
  V[tid] = gv[pair*260 + tid];
  if (tid < 2) RT[tid] = gv[pair*260 + 256 + tid];
  __syncthreads();
  float R = RT[0], T = RT[1];
  #pragma unroll
  for (int u = 0; u < 3; ++u){
    int col = tid + 256*u;
    const unsigned* wr = (const unsigned*)(w2T + (size_t)col*256);
    float acc = 0.f;
    #pragma unroll 8
    for (int k2 = 0; k2 < 128; ++k2){
      unsigned ww = wr[k2];
      acc += V[2*k2]*lo_f(ww) + V[2*k2+1]*hi_f(ww);
    }
    geo[(size_t)pair*DD + col] = f_bits(g2g[col]*(acc + b2g[col]*R - T)*(1.f/384.f) + be2g[col]);
  }
}

// ---------------- per-superpoint scatter mean ----------------
__global__ __launch_bounds__(256) void k_scatter(
    const int* __restrict__ lab, const float* __restrict__ feat,
    const unsigned short* __restrict__ geo,
    float* __restrict__ meanf, float* __restrict__ meang, float* __restrict__ cntw)
{
  __shared__ int ls[NN];
  __shared__ float sf[DD], sg[DD];
  __shared__ int cnt;
  const int tid = threadIdx.x;
  const int b = blockIdx.x / SS, s = blockIdx.x % SS;
  for (int n = tid; n < NN; n += 256) ls[n] = lab[b*NN + n];
  for (int c = tid; c < DD; c += 256){ sf[c]=0.f; sg[c]=0.f; }
  if (tid == 0) cnt = 0;
  __syncthreads();
  for (int n = 0; n < NN; ++n){
    if (ls[n] == s){
      if (tid == 0) ++cnt;
      const float* fr = feat + (size_t)(b*NN+n)*DD;
      const unsigned short* gr = geo + (size_t)(b*NN+n)*DD;
      for (int c = tid; c < DD; c += 256){ sf[c] += fr[c]; sg[c] += bits_f(gr[c]); }
    }
  }
  __syncthreads();
  float cf = (float)cnt;
  float denom = fmaxf(cf, 1.f);
  size_t base = (size_t)(b*SS+s)*DD;
  for (int c = tid; c < DD; c += 256){ meanf[base+c] = sf[c]/denom; meang[base+c] = sg[c]/denom; }
  if (tid == 0) cntw[b*SS+s] = cf;
}

// ---------------- aggregator MLP + combine with mean_g ----------------
__global__ __launch_bounds__(256) void k_agg(
    const float* __restrict__ meanf, const float* __restrict__ meang,
    const float* __restrict__ w1g, const float* __restrict__ b1g,
    const float* __restrict__ g1g, const float* __restrict__ be1g,
    const float* __restrict__ w2g, const float* __restrict__ b2g,
    const float* __restrict__ g2g, const float* __restrict__ be2g,
    float* __restrict__ comb)
{
  __shared__ float xr[DD];
  __shared__ float hr[HH];
  __shared__ float red[8];
  const int tid = threadIdx.x;
  const size_t base = (size_t)blockIdx.x * DD;
  for (int c = tid; c < DD; c += 256) xr[c] = meanf[base + c];
  __syncthreads();
  float a = b1g[tid];
  #pragma unroll 4
  for (int k = 0; k < DD; ++k) a += xr[k]*w1g[k*HH + tid];
  float s = a, q = a*a;
  for (int m = 32; m >= 1; m >>= 1){ s += __shfl_xor(s,m); q += __shfl_xor(q,m); }
  if ((tid & 63) == 0){ red[tid>>6] = s; red[4+(tid>>6)] = q; }
  __syncthreads();
  s = red[0]+red[1]+red[2]+red[3]; q = red[4]+red[5]+red[6]+red[7];
  float mean = s*(1.f/HH), var = q*(1.f/HH) - mean*mean, rstd = rsqrtf(var + 1e-5f);
  float h = fmaxf((a-mean)*rstd*g1g[tid] + be1g[tid], 0.f);
  hr[tid] = h;
  __syncthreads();
  float a2[3];
  #pragma unroll
  for (int u = 0; u < 3; ++u){
    int c = tid + 256*u;
    float t = b2g[c];
    #pragma unroll 4
    for (int k = 0; k < HH; ++k) t += hr[k]*w2g[k*DD + c];
    a2[u] = t;
  }
  float s2 = a2[0]+a2[1]+a2[2], q2 = a2[0]*a2[0]+a2[1]*a2[1]+a2[2]*a2[2];
  for (int m = 32; m >= 1; m >>= 1){ s2 += __shfl_xor(s2,m); q2 += __shfl_xor(q2,m); }
  __syncthreads();
  if ((tid & 63) == 0){ red[tid>>6] = s2; red[4+(tid>>6)] = q2; }
  __syncthreads();
  s2 = red[0]+red[1]+red[2]+red[3]; q2 = red[4]+red[5]+red[6]+red[7];
  float mean2 = s2*(1.f/DD), rstd2 = rsqrtf(q2*(1.f/DD) - mean2*mean2 + 1e-5f);
  #pragma unroll
  for (int u = 0; u < 3; ++u){
    int c = tid + 256*u;
    comb[base + c] = (a2[u]-mean2)*rstd2*g2g[c] + be2g[c] + meang[base + c];
  }
}

// ---------------- gather + enhanced (fp32 out) ----------------
__global__ void k_enhance(const float* __restrict__ feat, const int* __restrict__ lab,
                          const float* __restrict__ cntw, const float* __restrict__ comb,
                          float* __restrict__ enh)
{
  int idx = blockIdx.x * 256 + threadIdx.x;
  int c = idx % DD; int bn = idx / DD; int b = bn / NN;
  int l = lab[bn];
  float f = feat[idx];
  float cg = comb[(size_t)(b*SS + l)*DD + c];
  float cnt = cntw[b*SS + l];
  enh[idx] = (cnt >= 2.0f) ? (0.7f*f + 0.3f*cg) : f;
}

// ---------------- q/k/v projections via MFMA, barrier-free; q pre-scaled, bf16 out ----------------
__global__ __launch_bounds__(256, 4) void k_qkv(
    const float* __restrict__ enh, const unsigned short* __restrict__ geo,
    const short* __restrict__ wqT, const short* __restrict__ wkT, const short* __restrict__ wvT,
    const float* __restrict__ bq, const float* __restrict__ bk, const float* __restrict__ bv,
    unsigned short* __restrict__ qo, unsigned short* __restrict__ ko, unsigned short* __restrict__ vo)
{
  const int tid = threadIdx.x, blk = blockIdx.x;     // 216 = 3 mats * 24 rt * 3 ct
  const int m = blk / 72, rem = blk % 72;
  const int rt = rem / 3, ct = rem % 3;
  const int wave = tid >> 6, lane = tid & 63, quad = lane >> 4, l16 = lane & 15;
  const short* WT = (m==0)?wqT:(m==1)?wkT:wvT;
  const float* Bv = (m==0)?bq:(m==1)?bk:bv;
  unsigned short* Y = (m==0)?qo:(m==1)?ko:vo;
  const float oscale = (m==0)? 0.10206207261596577f : 1.0f;
  const int row0 = rt*32;
  const int col0 = ct*256 + wave*64;

  f32x4 acc[2][4];
  #pragma unroll
  for (int rb=0;rb<2;++rb)
    #pragma unroll
    for (int cb=0;cb<4;++cb) acc[rb][cb] = (f32x4){0.f,0.f,0.f,0.f};

  for (int ks = 0; ks < 24; ++ks){
    bf16x8 af[2];
    if (m == 0){
      #pragma unroll
      for (int rb=0;rb<2;++rb){
        const float* ap = enh + (size_t)(row0 + rb*16 + l16)*DD + ks*32 + quad*8;
        float x[8];
        *(float4*)&x[0] = *(const float4*)ap;
        *(float4*)&x[4] = *(const float4*)(ap+4);
        bf16x8 a;
        #pragma unroll
        for (int i=0;i<8;++i) a[i] = (short)f_bits(x[i]);
        af[rb] = a;
      }
    } else {
      #pragma unroll
      for (int rb=0;rb<2;++rb)
        af[rb] = *(const bf16x8*)&((const short*)geo)[(size_t)(row0 + rb*16 + l16)*DD + ks*32 + quad*8];
    }
    #pragma unroll
    for (int cb=0;cb<4;++cb){
      bf16x8 bw = *(const bf16x8*)&WT[(size_t)(col0 + cb*16 + l16)*DD + ks*32 + quad*8];
      #pragma unroll
      for (int rb=0;rb<2;++rb)
        acc[rb][cb] = __builtin_amdgcn_mfma_f32_16x16x32_bf16(af[rb], bw, acc[rb][cb], 0,0,0);
    }
  }
  #pragma unroll
  for (int cb=0;cb<4;++cb){
    int col = col0 + cb*16 + l16;
    float bb = Bv[col];
    #pragma unroll
    for (int rb=0;rb<2;++rb){
      #pragma unroll
      for (int r=0;r<4;++r){
        int row = row0 + rb*16 + quad*4 + r;
        Y[(size_t)row*DD + col] = f_bits((acc[rb][cb][r] + bb)*oscale);
      }
    }
  }
}

// ---------------- attention: per (b, head, 32-q tile); bf16 K/V tiles in LDS ----------------
__global__ __launch_bounds__(256) void k_attn(
    const unsigned short* __restrict__ qws, const unsigned short* __restrict__ kws,
    const unsigned short* __restrict__ vws, unsigned short* __restrict__ ows)
{
  __shared__ short kt[64*104];
  __shared__ short vt[64*104];
  __shared__ float st[32*66];
  __shared__ float lsum[32];
  const int tid = threadIdx.x;
  const int blk = blockIdx.x;
  const int b = blk / (NHH*12); int rem = blk % (NHH*12);
  const int h = rem / 12; const int qt = rem % 12; const int q0 = qt*32;
  const int sq = tid >> 3, jp = tid & 7;
  const int qp = tid >> 4, dp = tid & 15;
  unsigned qreg[48];
  {
    const unsigned* qr = (const unsigned*)(qws + (size_t)(b*NN + q0 + sq)*DD + h*DHH);
    #pragma unroll
    for (int d2 = 0; d2 < 48; ++d2) qreg[d2] = qr[d2];
  }
  if (tid < 32) lsum[tid] = 0.f;
  float Oacc[2][6];
  #pragma unroll
  for (int a = 0; a < 2; ++a)
    #pragma unroll
    for (int m = 0; m < 6; ++m) Oacc[a][m] = 0.f;

  for (int jt = 0; jt < 6; ++jt){
    const int j0 = jt * 64;
    __syncthreads();
    for (int x = tid; x < 64*48; x += 256){
      int jl = x / 48, du = x % 48;
      size_t rowoff = (size_t)(b*NN + j0 + jl)*DD + h*DHH;
      ((unsigned*)&kt[jl*104])[du] = ((const unsigned*)(kws + rowoff))[du];
      ((unsigned*)&vt[jl*104])[du] = ((const unsigned*)(vws + rowoff))[du];
    }
    __syncthreads();
    float lpart = 0.f;
    #pragma unroll
    for (int jj = 0; jj < 8; ++jj){
      int j = jp*8 + jj;
      const uint4* kr4 = (const uint4*)&kt[j*104];
      float s = 0.f;
      #pragma unroll
      for (int d4 = 0; d4 < 12; ++d4){
        uint4 kk = kr4[d4];
        unsigned q0r = qreg[4*d4], q1r = qreg[4*d4+1], q2r = qreg[4*d4+2], q3r = qreg[4*d4+3];
        s += lo_f(kk.x)*lo_f(q0r) + hi_f(kk.x)*hi_f(q0r);
        s += lo_f(kk.y)*lo_f(q1r) + hi_f(kk.y)*hi_f(q1r);
        s += lo_f(kk.z)*lo_f(q2r) + hi_f(kk.z)*hi_f(q2r);
        s += lo_f(kk.w)*lo_f(q3r) + hi_f(kk.w)*hi_f(q3r);
      }
      float p = __expf(s);
      st[sq*66 + j] = p;
      lpart += p;
    }
    lpart += __shfl_xor(lpart,1);
    lpart += __shfl_xor(lpart,2);
    lpart += __shfl_xor(lpart,4);
    if (jp == 0) lsum[sq] += lpart;
    __syncthreads();
    #pragma unroll 4
    for (int j = 0; j < 64; ++j){
      float p0 = st[(2*qp)*66 + j];
      float p1 = st[(2*qp+1)*66 + j];
      const unsigned* vr = (const unsigned*)&vt[j*104 + dp*6];
      #pragma unroll
      for (int m = 0; m < 3; ++m){
        unsigned vv = vr[m];
        float v0 = lo_f(vv), v1 = hi_f(vv);
        Oacc[0][2*m]   += p0*v0; Oacc[0][2*m+1] += p0*v1;
        Oacc[1][2*m]   += p1*v0; Oacc[1][2*m+1] += p1*v1;
      }
    }
  }
  __syncthreads();
  float l0 = 1.f / lsum[2*qp], l1 = 1.f / lsum[2*qp+1];
  size_t ob = (size_t)(b*NN + q0)*DD + h*DHH + dp*6;
  #pragma unroll
  for (int m = 0; m < 6; ++m){
    ows[ob + (size_t)(2*qp)*DD + m]   = f_bits(Oacc[0][m]*l0);
    ows[ob + (size_t)(2*qp+1)*DD + m] = f_bits(Oacc[1][m]*l1);
  }
}

// ---------------- output projection via MFMA + residual, fp32 out ----------------
__global__ __launch_bounds__(256, 4) void k_out(
    const unsigned short* __restrict__ ows, const float* __restrict__ enh,
    const short* __restrict__ woT, const float* __restrict__ bo, float* __restrict__ out)
{
  const int tid = threadIdx.x, blk = blockIdx.x;   // 72 = 24 rt * 3 ct
  const int rt = blk / 3, ct = blk % 3;
  const int wave = tid >> 6, lane = tid & 63, quad = lane >> 4, l16 = lane & 15;
  const int row0 = rt*32;
  const int col0 = ct*256 + wave*64;
  f32x4 acc[2][4];
  #pragma unroll
  for (int rb=0;rb<2;++rb)
    #pragma unroll
    for (int cb=0;cb<4;++cb) acc[rb][cb] = (f32x4){0.f,0.f,0.f,0.f};
  for (int ks = 0; ks < 24; ++ks){
    bf16x8 af[2];
    #pragma unroll
    for (int rb=0;rb<2;++rb)
      af[rb] = *(const bf16x8*)&((const short*)ows)[(size_t)(row0 + rb*16 + l16)*DD + ks*32 + quad*8];
    #pragma unroll
    for (int cb=0;cb<4;++cb){
      bf16x8 bw = *(const bf16x8*)&woT[(size_t)(col0 + cb*16 + l16)*DD + ks*32 + quad*8];
      #pragma unroll
      for (int rb=0;rb<2;++rb)
        acc[rb][cb] = __builtin_amdgcn_mfma_f32_16x16x32_bf16(af[rb], bw, acc[rb][cb], 0,0,0);
    }
  }
  #pragma unroll
  for (int cb=0;cb<4;++cb){
    int col = col0 + cb*16 + l16;
    float bb = bo[col];
    #pragma unroll
    for (int rb=0;rb<2;++rb){
      #pragma unroll
      for (int r=0;r<4;++r){
        size_t idx = (size_t)(row0 + rb*16 + quad*4 + r)*DD + col;
        out[idx] = enh[idx] + 0.5f*(acc[rb][cb][r] + bb);
      }
    }
  }
}

extern "C" void kernel_launch(void* const* d_in, const int* in_sizes, int n_in,
                              void* d_out, int out_size, void* d_ws, size_t ws_size,
                              hipStream_t stream) {
  const float* coord = (const float*)d_in[0];
  const float* feat  = (const float*)d_in[1];
  const int*   lab   = (const int*)d_in[2];
  const float* ge_w1 = (const float*)d_in[3];
  const float* ge_b1 = (const float*)d_in[4];
  const float* ge_g1 = (const float*)d_in[5];
  const float* ge_be1= (const float*)d_in[6];
  const float* ge_w2 = (const float*)d_in[7];
  const float* ge_b2 = (const float*)d_in[8];
  const float* ge_g2 = (const float*)d_in[9];
  const float* ge_be2= (const float*)d_in[10];
  const float* ag_w1 = (const float*)d_in[11];
  const float* ag_b1 = (const float*)d_in[12];
  const float* ag_g1 = (const float*)d_in[13];
  const float* ag_be1= (const float*)d_in[14];
  const float* ag_w2 = (const float*)d_in[15];
  const float* ag_b2 = (const float*)d_in[16];
  const float* ag_g2 = (const float*)d_in[17];
  const float* ag_be2= (const float*)d_in[18];
  const float* wq = (const float*)d_in[19];
  const float* bq = (const float*)d_in[20];
  const float* wk = (const float*)d_in[21];
  const float* bk = (const float*)d_in[22];
  const float* wv = (const float*)d_in[23];
  const float* bv = (const float*)d_in[24];
  const float* wo = (const float*)d_in[25];
  const float* bo = (const float*)d_in[26];

  // Workspace layout, 13,138,176 B total. Overlays (all producer-after-consumer safe):
  //  ow over geo_bf (geo last read: k_qkv);  comb over w2T (w2T last read: k_geofin);
  //  cntw over w1t (last read: k_geo);  meanf/meang over gv (last read: k_geofin).
  char* w = (char*)d_ws;
  unsigned short* geo_bf = (unsigned short*)(w);              // 1,179,648
  float*          enh_f  = (float*)(w + 1179648);             // 2,359,296
  unsigned short* qw_bf  = (unsigned short*)(w + 3538944);    // 1,179,648
  unsigned short* kw_bf  = (unsigned short*)(w + 4718592);    // 1,179,648
  unsigned short* vw_bf  = (unsigned short*)(w + 5898240);    // 1,179,648
  short*          w2T    = (short*)(w + 7077888);             //   393,216
  float*          comb   = (float*)(w + 7077888);             //   overlay
  short*          w1t    = (short*)(w + 7471104);             //    16,384
  float*          cntw   = (float*)(w + 7471104);             //   overlay
  short*          Gm     = (short*)(w + 7487488);             //   131,072
  float*          s1v    = (float*)(w + 7618560);             //     1,024
  float*          wbv    = (float*)(w + 7619584);             //     1,024
  float*          gscal  = (float*)(w + 7620608);             //       256
  float*          gv     = (float*)(w + 7620864);             //   798,720
  float*          meanf  = (float*)(w + 7620864);             //   overlay
  float*          meang  = (float*)(w + 8014080);             //   overlay
  short*          wqT    = (short*)(w + 8419584);             // 1,179,648
  short*          wkT    = (short*)(w + 9599232);             // 1,179,648
  short*          wvT    = (short*)(w + 10778880);            // 1,179,648
  short*          woT    = (short*)(w + 11958528);            // 1,179,648
  unsigned short* ow_bf  = geo_bf;

  hipLaunchKernelGGL(k_prep,    dim3(10764), dim3(256), 0, stream,
                     ge_w2, w2T, gv, ge_w1, w1t, wq, wk, wv, wo, wqT, wkT, wvT, woT);
  hipLaunchKernelGGL(k_gprep,   dim3(257),   dim3(256), 0, stream,
                     w2T, ge_b2, Gm, s1v, wbv, gscal);
  hipLaunchKernelGGL(k_geo,     dim3(4608),  dim3(512), 0, stream,
                     coord, w1t, ge_b1, ge_g1, ge_be1, Gm, s1v, wbv, gscal, gv);
  hipLaunchKernelGGL(k_geofin,  dim3(768),   dim3(256), 0, stream,
                     gv, w2T, ge_b2, ge_g2, ge_be2, geo_bf);
  hipLaunchKernelGGL(k_scatter, dim3(128),   dim3(256), 0, stream,
                     lab, feat, geo_bf, meanf, meang, cntw);
  hipLaunchKernelGGL(k_agg,     dim3(128),   dim3(256), 0, stream,
                     meanf, meang, ag_w1, ag_b1, ag_g1, ag_be1, ag_w2, ag_b2, ag_g2, ag_be2, comb);
  hipLaunchKernelGGL(k_enhance, dim3(2304),  dim3(256), 0, stream,
                     feat, lab, cntw, comb, enh_f);
  hipLaunchKernelGGL(k_qkv,     dim3(216),   dim3(256), 0, stream,
                     enh_f, geo_bf, wqT, wkT, wvT, bq, bk, bv, qw_bf, kw_bf, vw_bf);
  hipLaunchKernelGGL(k_attn,    dim3(192),   dim3(256), 0, stream,
                     qw_bf, kw_bf, vw_bf, ow_bf);
  hipLaunchKernelGGL(k_out,     dim3(72),    dim3(256), 0, stream,
                     ow_bf, enh_f, woT, bo, (float*)d_out);
}

// Round 8
// 630.796 us; speedup vs baseline: 1.5167x; 1.0948x over previous
//
#include <hip/hip_runtime.h>
#include <hip/hip_bf16.h>
#include <stdint.h>
#include <stddef.h>

#define BB 2
#define NN 384
#define DD 768
#define HH 256
#define SS 64
#define NHH 8
#define DHH 96

typedef __attribute__((ext_vector_type(8))) short bf16x8;
typedef __attribute__((ext_vector_type(4))) float f32x4;

__device__ __forceinline__ float bits_f(unsigned short u){
  unsigned x = ((unsigned)u) << 16; float f; __builtin_memcpy(&f, &x, 4); return f;
}
__device__ __forceinline__ unsigned short f_bits(float a){
  unsigned x; __builtin_memcpy(&x, &a, 4);
  unsigned r = x + 0x7fffu + ((x >> 16) & 1u);
  return (unsigned short)(r >> 16);
}
__device__ __forceinline__ float lo_f(unsigned u){ unsigned x = u << 16; float f; __builtin_memcpy(&f,&x,4); return f; }
__device__ __forceinline__ float hi_f(unsigned u){ unsigned x = u & 0xffff0000u; float f; __builtin_memcpy(&f,&x,4); return f; }

// ================= prep: zeroing + all transposes (LDS-tiled, coalesced) =================
__global__ __launch_bounds__(256) void k_prep(
    const float* __restrict__ w2, const float* __restrict__ w1g,
    const float* __restrict__ wq, const float* __restrict__ wk,
    const float* __restrict__ wv, const float* __restrict__ wo,
    float* __restrict__ zf, short* __restrict__ w2T, short* __restrict__ w2r,
    short* __restrict__ wqT, short* __restrict__ wkT, short* __restrict__ wvT,
    short* __restrict__ woT, short* __restrict__ w1t)
{
  __shared__ short tile[64*66];
  const int tid = threadIdx.x, blk = blockIdx.x;
  if (blk < 1549){
    int idx = blk*256 + tid;
    if (idx < 396416) zf[idx] = 0.f;
    return;
  }
  if (blk < 1597){            // w2 [256,768] -> w2T [768,256]
    int t = blk - 1549;
    int r0 = (t/12)*64, c0 = (t%12)*64;
    int g = tid >> 6, c = tid & 63;
    #pragma unroll
    for (int i=0;i<16;++i){
      int r = i*4 + g;
      tile[r*66 + c] = (short)f_bits(w2[(size_t)(r0+r)*768 + c0 + c]);
    }
    __syncthreads();
    #pragma unroll
    for (int i=0;i<16;++i){
      int cc = i*4 + g, rr = c;
      w2T[(size_t)(c0+cc)*256 + r0 + rr] = tile[rr*66 + cc];
    }
    return;
  }
  if (blk < 2365){            // w2r: row-major bf16 copy
    int idx = (blk-1597)*256 + tid;
    w2r[idx] = (short)f_bits(w2[idx]);
    return;
  }
  if (blk < 2941){            // attn weights [768,768] -> T[n][k]
    int t = blk - 2365;
    int mat = t / 144, tt = t % 144;
    const float* W = (mat==0)?wq:(mat==1)?wk:(mat==2)?wv:wo;
    short* T = (mat==0)?wqT:(mat==1)?wkT:(mat==2)?wvT:woT;
    int r0 = (tt/12)*64, c0 = (tt%12)*64;
    int g = tid >> 6, c = tid & 63;
    #pragma unroll
    for (int i=0;i<16;++i){
      int r = i*4 + g;
      tile[r*66 + c] = (short)f_bits(W[(size_t)(r0+r)*768 + c0 + c]);
    }
    __syncthreads();
    #pragma unroll
    for (int i=0;i<16;++i){
      int cc = i*4 + g, rr = c;
      T[(size_t)(c0+cc)*768 + r0 + rr] = tile[rr*66 + cc];
    }
    return;
  }
  {                           // w1t [256c][32k], K padded
    int idx = (blk-2941)*256 + tid;
    int c = idx >> 5, kk = idx & 31;
    w1t[idx] = (kk < 9) ? (short)f_bits(w1g[kk*256 + c]) : (short)0;
  }
}

// ================= Gram prep: Gm[288][256] (rows 256=s1,257=wb,258+=0), gscal, w1 stats =================
__global__ __launch_bounds__(256) void k_gprep(const short* __restrict__ w2T,
                                               const float* __restrict__ b2,
                                               const short* __restrict__ w1t,
                                               const float* __restrict__ b1,
                                               short* __restrict__ Gm, float* __restrict__ gscal,
                                               float* __restrict__ g1s){
  __shared__ float red[8];
  const int tid = threadIdx.x, blk = blockIdx.x;
  const unsigned short* wt = (const unsigned short*)w2T;
  if (blk < 256){
    float acc = 0.f;
    for (int c = 0; c < 768; ++c){
      float a = bits_f(wt[c*256 + blk]);
      float x = bits_f(wt[c*256 + tid]);
      acc += a * x;
    }
    Gm[blk*256 + tid] = (short)f_bits(acc);
  } else if (blk == 256){
    float sa = 0.f, wa = 0.f;
    for (int c = 0; c < 768; ++c){
      float x = bits_f(wt[c*256 + tid]);
      float bb = b2[c];
      sa += x; wa += x * bb;
    }
    Gm[256*256 + tid] = (short)f_bits(sa);
    Gm[257*256 + tid] = (short)f_bits(wa);
    #pragma unroll
    for (int rr = 258; rr < 288; ++rr) Gm[rr*256 + tid] = 0;
    float pb = 0.f, pbb = 0.f;
    for (int c = tid; c < 768; c += 256){ float bb = b2[c]; pb += bb; pbb += bb*bb; }
    for (int m = 32; m >= 1; m >>= 1){ pb += __shfl_xor(pb,m); pbb += __shfl_xor(pbb,m); }
    if ((tid & 63) == 0){ red[tid>>6] = pb; red[4+(tid>>6)] = pbb; }
    __syncthreads();
    if (tid == 0){ gscal[0] = red[0]+red[1]+red[2]+red[3]; gscal[1] = red[4]+red[5]+red[6]+red[7]; }
  } else {
    // g1s[0..8]=s1a, [9..17]=w1b1, [18..98]=G1(9x9), [99]=Sb1, [100]=Sb1b
    const unsigned short* w1u = (const unsigned short*)w1t;
    if (tid < 81){
      int i = tid / 9, j = tid % 9;
      float acc = 0.f;
      for (int c = 0; c < 256; ++c)
        acc += bits_f(w1u[c*32 + i]) * bits_f(w1u[c*32 + j]);
      g1s[18 + tid] = acc;
    } else if (tid < 90){
      int i = tid - 81;
      float sa = 0.f, sb = 0.f;
      for (int c = 0; c < 256; ++c){
        float x = bits_f(w1u[c*32 + i]);
        sa += x; sb += x * b1[c];
      }
      g1s[i] = sa; g1s[9 + i] = sb;
    } else if (tid == 90){
      float pb = 0.f, pbb = 0.f;
      for (int c = 0; c < 256; ++c){ float bb = b1[c]; pb += bb; pbb += bb*bb; }
      g1s[99] = pb; g1s[100] = pbb;
    }
  }
}

// ================= geometric encoder; WG=(pair,jt), 256 thr, 4 waves =================
__global__ __launch_bounds__(256, 4) void k_geo(
    const float* __restrict__ coord, const short* __restrict__ w1t,
    const float* __restrict__ b1g, const float* __restrict__ g1g, const float* __restrict__ be1g,
    const short* __restrict__ Gm, const float* __restrict__ gscal,
    const float* __restrict__ g1s, float* __restrict__ gv)
{
  __shared__ short relbf[64*36];
  __shared__ short h_bf[64*256];   // chunk-swizzled: phys_chunk=((col>>3)+row)&31
  __shared__ float rmean[64], rrstd[64];
  __shared__ float msum[64], wbsum[64], qsum[64];

  const int tid = threadIdx.x;
  const int pair = blockIdx.x % 768;
  const int jt   = blockIdx.x / 768;
  const int j0 = jt * 64;
  const int b = pair / NN;

  // ---- phase 1: rel rows + exact LN1 stats via 9x9 Gram
  if (tid < 64){
    int j = j0 + tid;
    float cix = coord[pair*3+0], ciy = coord[pair*3+1], ciz = coord[pair*3+2];
    float dx = cix - coord[(b*NN+j)*3+0];
    float dy = ciy - coord[(b*NN+j)*3+1];
    float dz = ciz - coord[(b*NN+j)*3+2];
    float dist = sqrtf(dx*dx + dy*dy + dz*dz);
    float inv = 1.f / fmaxf(dist, 1e-12f);
    float x = dx*inv, y = dy*inv, z = dz*inv;
    float rv[9];
    rv[0]=dist; rv[1]=x; rv[2]=y; rv[3]=z; rv[4]=0.f; rv[5]=0.f;
    rv[6]=y*z; rv[7]=x*y; rv[8]=x*z;
    short* rr = &relbf[tid*36];
    float rbf[9];
    #pragma unroll
    for (int k=0;k<9;++k){
      unsigned short hb = f_bits(rv[k]);
      rr[k] = (short)hb; rbf[k] = bits_f(hb);
    }
    #pragma unroll
    for (int k=9;k<32;++k) rr[k]=0;
    float s = g1s[99], ssq = g1s[100];
    #pragma unroll
    for (int i=0;i<9;++i){
      s += rbf[i]*g1s[i];
      ssq += 2.f*rbf[i]*g1s[9+i];
      #pragma unroll
      for (int jj=0;jj<9;++jj) ssq += rbf[i]*rbf[jj]*g1s[18+i*9+jj];
    }
    float mean = s*(1.f/256.f);
    float var  = ssq*(1.f/256.f) - mean*mean;
    rmean[tid] = mean; rrstd[tid] = rsqrtf(var + 1e-5f);
  } else if (tid < 128){
    qsum[tid-64] = 0.f;
  }
  __syncthreads();

  const int wave = tid >> 6, lane = tid & 63, quad = lane >> 4, l16 = lane & 15;

  // ---- phase 2: MFMA mm1 + in-register LN1/ReLU -> h_bf (no shuffles/atomics)
  {
    bf16x8 af[4];
    #pragma unroll
    for (int rb=0;rb<4;++rb)
      af[rb] = *(const bf16x8*)&relbf[(rb*16 + l16)*36 + quad*8];
    f32x4 hacc[4][4];
    #pragma unroll
    for (int ci=0;ci<4;++ci){
      int cb = wave*4 + ci;
      bf16x8 bfw = *(const bf16x8*)&w1t[(cb*16 + l16)*32 + quad*8];
      #pragma unroll
      for (int rb=0;rb<4;++rb)
        hacc[ci][rb] = __builtin_amdgcn_mfma_f32_16x16x32_bf16(af[rb], bfw, (f32x4){0.f,0.f,0.f,0.f}, 0,0,0);
    }
    f32x4 rmv[4], rsv[4];
    #pragma unroll
    for (int rb=0;rb<4;++rb){
      rmv[rb] = *(const f32x4*)&rmean[rb*16 + quad*4];
      rsv[rb] = *(const f32x4*)&rrstd[rb*16 + quad*4];
    }
    #pragma unroll
    for (int ci=0;ci<4;++ci){
      int col = (wave*4+ci)*16 + l16;
      float b1c = b1g[col], g1c = g1g[col], be1c = be1g[col];
      int chb = col >> 3, lo = col & 7;
      #pragma unroll
      for (int rb=0;rb<4;++rb){
        #pragma unroll
        for (int r=0;r<4;++r){
          int row = rb*16 + quad*4 + r;
          float hn = (hacc[ci][rb][r] + b1c - rmv[rb][r]) * rsv[rb][r] * g1c + be1c;
          h_bf[row*256 + ((chb + row)&31)*8 + lo] = (short)f_bits(fmaxf(hn, 0.f));
        }
      }
    }
  }
  __syncthreads();

  // ---- phase 3: U = H@Gm_ext; wave0 ext tile -> msum/wbsum; Q_j = sum U.h
  {
    f32x4 acc[4][4];
    #pragma unroll
    for (int ci=0;ci<4;++ci)
      #pragma unroll
      for (int rb=0;rb<4;++rb) acc[ci][rb] = (f32x4){0.f,0.f,0.f,0.f};
    f32x4 eacc[4];
    #pragma unroll
    for (int rb=0;rb<4;++rb) eacc[rb] = (f32x4){0.f,0.f,0.f,0.f};
    for (int ks=0;ks<8;++ks){
      bf16x8 a4[4];
      #pragma unroll
      for (int rb=0;rb<4;++rb){
        int row = rb*16 + l16;
        a4[rb] = *(const bf16x8*)&h_bf[row*256 + (((ks*4 + quad) + row)&31)*8];
      }
      #pragma unroll
      for (int ci=0;ci<4;++ci){
        int n = (wave*4+ci)*16 + l16;
        bf16x8 bg = *(const bf16x8*)&Gm[n*256 + ks*32 + quad*8];
        #pragma unroll
        for (int rb=0;rb<4;++rb)
          acc[ci][rb] = __builtin_amdgcn_mfma_f32_16x16x32_bf16(a4[rb], bg, acc[ci][rb], 0,0,0);
      }
      if (wave == 0){
        bf16x8 bge = *(const bf16x8*)&Gm[(256 + l16)*256 + ks*32 + quad*8];
        #pragma unroll
        for (int rb=0;rb<4;++rb)
          eacc[rb] = __builtin_amdgcn_mfma_f32_16x16x32_bf16(a4[rb], bge, eacc[rb], 0,0,0);
      }
    }
    if (wave == 0 && l16 < 2){
      float* dst = (l16 == 0) ? msum : wbsum;
      #pragma unroll
      for (int rb=0;rb<4;++rb)
        #pragma unroll
        for (int r=0;r<4;++r) dst[rb*16 + quad*4 + r] = eacc[rb][r];
    }
    #pragma unroll
    for (int rb=0;rb<4;++rb){
      #pragma unroll
      for (int r=0;r<4;++r){
        int row = rb*16 + quad*4 + r;
        float qp = 0.f;
        #pragma unroll
        for (int ci=0;ci<4;++ci){
          int col = (wave*4+ci)*16 + l16;
          float hv = bits_f((unsigned short)h_bf[row*256 + (((col>>3)+row)&31)*8 + (col&7)]);
          qp += acc[ci][rb][r] * hv;
        }
        qp += __shfl_xor(qp,1);
        qp += __shfl_xor(qp,2);
        qp += __shfl_xor(qp,4);
        qp += __shfl_xor(qp,8);
        if (l16 == 0) atomicAdd(&qsum[row], qp);
      }
    }
  }
  __syncthreads();
  if (tid < 64){
    float Sb = gscal[0], Sbb = gscal[1];
    float m2 = (msum[tid] + Sb)*(1.f/768.f);
    float ssq = qsum[tid] + 2.f*wbsum[tid] + Sbb;
    float var = ssq*(1.f/768.f) - m2*m2;
    rmean[tid] = m2; rrstd[tid] = rsqrtf(var + 1e-5f);
  }
  __syncthreads();
  if (tid < 64){
    float rr = rrstd[tid], tt = rmean[tid]*rrstd[tid];
    for (int m = 32; m >= 1; m >>= 1){ rr += __shfl_xor(rr,m); tt += __shfl_xor(tt,m); }
    if (tid == 0){
      atomicAdd(&gv[pair*260 + 256], rr);
      atomicAdd(&gv[pair*260 + 257], tt);
    }
  }
  {
    int col = tid, chb = col >> 3, lo = col & 7;
    float v = 0.f;
    #pragma unroll 8
    for (int j = 0; j < 64; ++j)
      v += rrstd[j] * bits_f((unsigned short)h_bf[j*256 + ((chb + j)&31)*8 + lo]);
    atomicAdd(&gv[pair*260 + col], v);
  }
}

// ================= finalize geo (coalesced w2r reads) =================
__global__ __launch_bounds__(256) void k_geofin(
    const float* __restrict__ gv, const short* __restrict__ w2r,
    const float* __restrict__ b2g, const float* __restrict__ g2g,
    const float* __restrict__ be2g, unsigned short* __restrict__ geo){
  __shared__ float V[256];
  __shared__ float RT[2];
  const int tid = threadIdx.x, pair = blockIdx.x;
  V[tid] = gv[pair*260 + tid];
  if (tid < 2) RT[tid] = gv[pair*260 + 256 + tid];
  __syncthreads();
  float R = RT[0], T = RT[1];
  const unsigned short* wr = (const unsigned short*)w2r;
  float a0 = 0.f, a1 = 0.f, a2 = 0.f;
  #pragma unroll 4
  for (int k = 0; k < 256; ++k){
    float vk = V[k];
    const unsigned short* row = wr + (size_t)k*768;
    a0 += vk * bits_f(row[tid]);
    a1 += vk * bits_f(row[tid+256]);
    a2 += vk * bits_f(row[tid+512]);
  }
  size_t base = (size_t)pair*DD;
  geo[base + tid]       = f_bits(g2g[tid]    *(a0 + b2g[tid]    *R - T)*(1.f/384.f) + be2g[tid]);
  geo[base + tid + 256] = f_bits(g2g[tid+256]*(a1 + b2g[tid+256]*R - T)*(1.f/384.f) + be2g[tid+256]);
  geo[base + tid + 512] = f_bits(g2g[tid+512]*(a2 + b2g[tid+512]*R - T)*(1.f/384.f) + be2g[tid+512]);
}

// ================= per-point scatter (atomics) =================
__global__ __launch_bounds__(256) void k_scat(
    const int* __restrict__ lab, const float* __restrict__ feat,
    const unsigned short* __restrict__ geo,
    float* __restrict__ mf, float* __restrict__ mg, float* __restrict__ cntw)
{
  const int tid = threadIdx.x, bn = blockIdx.x;
  const int b = bn / NN;
  const int s = lab[bn];
  const size_t base = (size_t)(b*SS + s)*DD;
  if (tid == 0) atomicAdd(&cntw[b*SS + s], 1.0f);
  #pragma unroll
  for (int u = 0; u < 3; ++u){
    int c = tid + 256*u;
    atomicAdd(&mf[base + c], feat[(size_t)bn*DD + c]);
    atomicAdd(&mg[base + c], bits_f(geo[(size_t)bn*DD + c]));
  }
}

// ================= aggregator MLP + combine =================
__global__ __launch_bounds__(256) void k_agg(
    const float* __restrict__ mf, const float* __restrict__ mg,
    const float* __restrict__ cntw,
    const float* __restrict__ w1g, const float* __restrict__ b1g,
    const float* __restrict__ g1g, const float* __restrict__ be1g,
    const float* __restrict__ w2g, const float* __restrict__ b2g,
    const float* __restrict__ g2g, const float* __restrict__ be2g,
    float* __restrict__ comb)
{
  __shared__ float xr[DD];
  __shared__ float hr[HH];
  __shared__ float red[8];
  const int tid = threadIdx.x;
  const size_t base = (size_t)blockIdx.x * DD;
  const float inv = 1.f / fmaxf(cntw[blockIdx.x], 1.f);
  for (int c = tid; c < DD; c += 256) xr[c] = mf[base + c]*inv;
  __syncthreads();
  float a = b1g[tid];
  #pragma unroll 4
  for (int k = 0; k < DD; ++k) a += xr[k]*w1g[k*HH + tid];
  float s = a, q = a*a;
  for (int m = 32; m >= 1; m >>= 1){ s += __shfl_xor(s,m); q += __shfl_xor(q,m); }
  if ((tid & 63) == 0){ red[tid>>6] = s; red[4+(tid>>6)] = q; }
  __syncthreads();
  s = red[0]+red[1]+red[2]+red[3]; q = red[4]+red[5]+red[6]+red[7];
  float mean = s*(1.f/HH), var = q*(1.f/HH) - mean*mean, rstd = rsqrtf(var + 1e-5f);
  float h = fmaxf((a-mean)*rstd*g1g[tid] + be1g[tid], 0.f);
  hr[tid] = h;
  __syncthreads();
  float a2[3];
  #pragma unroll
  for (int u = 0; u < 3; ++u){
    int c = tid + 256*u;
    float t = b2g[c];
    #pragma unroll 4
    for (int k = 0; k < HH; ++k) t += hr[k]*w2g[k*DD + c];
    a2[u] = t;
  }
  float s2 = a2[0]+a2[1]+a2[2], q2 = a2[0]*a2[0]+a2[1]*a2[1]+a2[2]*a2[2];
  for (int m = 32; m >= 1; m >>= 1){ s2 += __shfl_xor(s2,m); q2 += __shfl_xor(q2,m); }
  __syncthreads();
  if ((tid & 63) == 0){ red[tid>>6] = s2; red[4+(tid>>6)] = q2; }
  __syncthreads();
  s2 = red[0]+red[1]+red[2]+red[3]; q2 = red[4]+red[5]+red[6]+red[7];
  float mean2 = s2*(1.f/DD), rstd2 = rsqrtf(q2*(1.f/DD) - mean2*mean2 + 1e-5f);
  #pragma unroll
  for (int u = 0; u < 3; ++u){
    int c = tid + 256*u;
    comb[base + c] = (a2[u]-mean2)*rstd2*g2g[c] + be2g[c] + mg[base + c]*inv;
  }
}

// ================= gather + enhanced (fp32 + bf16 out) =================
__global__ void k_enhance(const float* __restrict__ feat, const int* __restrict__ lab,
                          const float* __restrict__ cntw, const float* __restrict__ comb,
                          float* __restrict__ enh, unsigned short* __restrict__ enhb)
{
  int idx = blockIdx.x * 256 + threadIdx.x;
  int c = idx % DD; int bn = idx / DD; int b = bn / NN;
  int l = lab[bn];
  float f = feat[idx];
  float cg = comb[(size_t)(b*SS + l)*DD + c];
  float cnt = cntw[b*SS + l];
  float e = (cnt >= 2.0f) ? (0.7f*f + 0.3f*cg) : f;
  enh[idx] = e;
  enhb[idx] = f_bits(e);
}

// ================= q/k/v projections via MFMA =================
__global__ __launch_bounds__(256, 4) void k_qkv(
    const unsigned short* __restrict__ enhb, const unsigned short* __restrict__ geo,
    const short* __restrict__ wqT, const short* __restrict__ wkT, const short* __restrict__ wvT,
    const float* __restrict__ bq, const float* __restrict__ bk, const float* __restrict__ bv,
    unsigned short* __restrict__ qo, unsigned short* __restrict__ ko, unsigned short* __restrict__ vo)
{
  const int tid = threadIdx.x, blk = blockIdx.x;
  const int m = blk / 72, rem = blk % 72;
  const int rt = rem / 3, ct = rem % 3;
  const int wave = tid >> 6, lane = tid & 63, quad = lane >> 4, l16 = lane & 15;
  const short* WT = (m==0)?wqT:(m==1)?wkT:wvT;
  const float* Bv = (m==0)?bq:(m==1)?bk:bv;
  unsigned short* Y = (m==0)?qo:(m==1)?ko:vo;
  const short* X = (const short*)((m==0)? enhb : geo);
  const float oscale = (m==0)? 0.10206207261596577f : 1.0f;
  const int row0 = rt*32;
  const int col0 = ct*256 + wave*64;

  f32x4 acc[2][4];
  #pragma unroll
  for (int rb=0;rb<2;++rb)
    #pragma unroll
    for (int cb=0;cb<4;++cb) acc[rb][cb] = (f32x4){0.f,0.f,0.f,0.f};

  for (int ks = 0; ks < 24; ++ks){
    bf16x8 af[2];
    #pragma unroll
    for (int rb=0;rb<2;++rb)
      af[rb] = *(const bf16x8*)&X[(size_t)(row0 + rb*16 + l16)*DD + ks*32 + quad*8];
    #pragma unroll
    for (int cb=0;cb<4;++cb){
      bf16x8 bw = *(const bf16x8*)&WT[(size_t)(col0 + cb*16 + l16)*DD + ks*32 + quad*8];
      #pragma unroll
      for (int rb=0;rb<2;++rb)
        acc[rb][cb] = __builtin_amdgcn_mfma_f32_16x16x32_bf16(af[rb], bw, acc[rb][cb], 0,0,0);
    }
  }
  #pragma unroll
  for (int cb=0;cb<4;++cb){
    int col = col0 + cb*16 + l16;
    float bb = Bv[col];
    #pragma unroll
    for (int rb=0;rb<2;++rb){
      #pragma unroll
      for (int r=0;r<4;++r){
        int row = row0 + rb*16 + quad*4 + r;
        Y[(size_t)row*DD + col] = f_bits((acc[rb][cb][r] + bb)*oscale);
      }
    }
  }
}

// ================= attention =================
__global__ __launch_bounds__(256) void k_attn(
    const unsigned short* __restrict__ qws, const unsigned short* __restrict__ kws,
    const unsigned short* __restrict__ vws, unsigned short* __restrict__ ows)
{
  __shared__ short kt[64*104];
  __shared__ short vt[64*104];
  __shared__ float st[32*66];
  __shared__ float lsum[32];
  const int tid = threadIdx.x;
  const int blk = blockIdx.x;
  const int b = blk / (NHH*12); int rem = blk % (NHH*12);
  const int h = rem / 12; const int qt = rem % 12; const int q0 = qt*32;
  const int sq = tid >> 3, jp = tid & 7;
  const int qp = tid >> 4, dp = tid & 15;
  unsigned qreg[48];
  {
    const unsigned* qr = (const unsigned*)(qws + (size_t)(b*NN + q0 + sq)*DD + h*DHH);
    #pragma unroll
    for (int d2 = 0; d2 < 48; ++d2) qreg[d2] = qr[d2];
  }
  if (tid < 32) lsum[tid] = 0.f;
  float Oacc[2][6];
  #pragma unroll
  for (int a = 0; a < 2; ++a)
    #pragma unroll
    for (int m = 0; m < 6; ++m) Oacc[a][m] = 0.f;

  for (int jt = 0; jt < 6; ++jt){
    const int j0 = jt * 64;
    __syncthreads();
    for (int x = tid; x < 64*48; x += 256){
      int jl = x / 48, du = x % 48;
      size_t rowoff = (size_t)(b*NN + j0 + jl)*DD + h*DHH;
      ((unsigned*)&kt[jl*104])[du] = ((const unsigned*)(kws + rowoff))[du];
      ((unsigned*)&vt[jl*104])[du] = ((const unsigned*)(vws + rowoff))[du];
    }
    __syncthreads();
    float lpart = 0.f;
    #pragma unroll
    for (int jj = 0; jj < 8; ++jj){
      int j = jp*8 + jj;
      const uint4* kr4 = (const uint4*)&kt[j*104];
      float s = 0.f;
      #pragma unroll
      for (int d4 = 0; d4 < 12; ++d4){
        uint4 kk = kr4[d4];
        unsigned q0r = qreg[4*d4], q1r = qreg[4*d4+1], q2r = qreg[4*d4+2], q3r = qreg[4*d4+3];
        s += lo_f(kk.x)*lo_f(q0r) + hi_f(kk.x)*hi_f(q0r);
        s += lo_f(kk.y)*lo_f(q1r) + hi_f(kk.y)*hi_f(q1r);
        s += lo_f(kk.z)*lo_f(q2r) + hi_f(kk.z)*hi_f(q2r);
        s += lo_f(kk.w)*lo_f(q3r) + hi_f(kk.w)*hi_f(q3r);
      }
      float p = __expf(s);
      st[sq*66 + j] = p;
      lpart += p;
    }
    lpart += __shfl_xor(lpart,1);
    lpart += __shfl_xor(lpart,2);
    lpart += __shfl_xor(lpart,4);
    if (jp == 0) lsum[sq] += lpart;
    __syncthreads();
    #pragma unroll 4
    for (int j = 0; j < 64; ++j){
      float p0 = st[(2*qp)*66 + j];
      float p1 = st[(2*qp+1)*66 + j];
      const unsigned* vr = (const unsigned*)&vt[j*104 + dp*6];
      #pragma unroll
      for (int m = 0; m < 3; ++m){
        unsigned vv = vr[m];
        float v0 = lo_f(vv), v1 = hi_f(vv);
        Oacc[0][2*m]   += p0*v0; Oacc[0][2*m+1] += p0*v1;
        Oacc[1][2*m]   += p1*v0; Oacc[1][2*m+1] += p1*v1;
      }
    }
  }
  __syncthreads();
  float l0 = 1.f / lsum[2*qp], l1 = 1.f / lsum[2*qp+1];
  size_t ob = (size_t)(b*NN + q0)*DD + h*DHH + dp*6;
  #pragma unroll
  for (int m = 0; m < 6; ++m){
    ows[ob + (size_t)(2*qp)*DD + m]   = f_bits(Oacc[0][m]*l0);
    ows[ob + (size_t)(2*qp+1)*DD + m] = f_bits(Oacc[1][m]*l1);
  }
}

// ================= output projection via MFMA + residual =================
__global__ __launch_bounds__(256, 4) void k_out(
    const unsigned short* __restrict__ ows, const float* __restrict__ enh,
    const short* __restrict__ woT, const float* __restrict__ bo, float* __restrict__ out)
{
  const int tid = threadIdx.x, blk = blockIdx.x;
  const int rt = blk / 3, ct = blk % 3;
  const int wave = tid >> 6, lane = tid & 63, quad = lane >> 4, l16 = lane & 15;
  const int row0 = rt*32;
  const int col0 = ct*256 + wave*64;
  f32x4 acc[2][4];
  #pragma unroll
  for (int rb=0;rb<2;++rb)
    #pragma unroll
    for (int cb=0;cb<4;++cb) acc[rb][cb] = (f32x4){0.f,0.f,0.f,0.f};
  for (int ks = 0; ks < 24; ++ks){
    bf16x8 af[2];
    #pragma unroll
    for (int rb=0;rb<2;++rb)
      af[rb] = *(const bf16x8*)&((const short*)ows)[(size_t)(row0 + rb*16 + l16)*DD + ks*32 + quad*8];
    #pragma unroll
    for (int cb=0;cb<4;++cb){
      bf16x8 bw = *(const bf16x8*)&woT[(size_t)(col0 + cb*16 + l16)*DD + ks*32 + quad*8];
      #pragma unroll
      for (int rb=0;rb<2;++rb)
        acc[rb][cb] = __builtin_amdgcn_mfma_f32_16x16x32_bf16(af[rb], bw, acc[rb][cb], 0,0,0);
    }
  }
  #pragma unroll
  for (int cb=0;cb<4;++cb){
    int col = col0 + cb*16 + l16;
    float bb = bo[col];
    #pragma unroll
    for (int rb=0;rb<2;++rb){
      #pragma unroll
      for (int r=0;r<4;++r){
        size_t idx = (size_t)(row0 + rb*16 + quad*4 + r)*DD + col;
        out[idx] = enh[idx] + 0.5f*(acc[rb][cb][r] + bb);
      }
    }
  }
}

extern "C" void kernel_launch(void* const* d_in, const int* in_sizes, int n_in,
                              void* d_out, int out_size, void* d_ws, size_t ws_size,
                              hipStream_t stream) {
  const float* coord = (const float*)d_in[0];
  const float* feat  = (const float*)d_in[1];
  const int*   lab   = (const int*)d_in[2];
  const float* ge_w1 = (const float*)d_in[3];
  const float* ge_b1 = (const float*)d_in[4];
  const float* ge_g1 = (const float*)d_in[5];
  const float* ge_be1= (const float*)d_in[6];
  const float* ge_w2 = (const float*)d_in[7];
  const float* ge_b2 = (const float*)d_in[8];
  const float* ge_g2 = (const float*)d_in[9];
  const float* ge_be2= (const float*)d_in[10];
  const float* ag_w1 = (const float*)d_in[11];
  const float* ag_b1 = (const float*)d_in[12];
  const float* ag_g1 = (const float*)d_in[13];
  const float* ag_be1= (const float*)d_in[14];
  const float* ag_w2 = (const float*)d_in[15];
  const float* ag_b2 = (const float*)d_in[16];
  const float* ag_g2 = (const float*)d_in[17];
  const float* ag_be2= (const float*)d_in[18];
  const float* wq = (const float*)d_in[19];
  const float* bq = (const float*)d_in[20];
  const float* wk = (const float*)d_in[21];
  const float* bk = (const float*)d_in[22];
  const float* wv = (const float*)d_in[23];
  const float* bv = (const float*)d_in[24];
  const float* wo = (const float*)d_in[25];
  const float* bo = (const float*)d_in[26];

  // Workspace 15,906,048 B. gv|mf|mg|cntw are contiguous -> single zero range.
  char* w = (char*)d_ws;
  unsigned short* geo_bf = (unsigned short*)(w);              // 1,179,648  [ow overlay]
  float*          enh_f  = (float*)(w + 1179648);             // 2,359,296
  unsigned short* enh_bf = (unsigned short*)(w + 3538944);    // 1,179,648
  unsigned short* qw_bf  = (unsigned short*)(w + 4718592);    // 1,179,648
  unsigned short* kw_bf  = (unsigned short*)(w + 5898240);    // 1,179,648
  unsigned short* vw_bf  = (unsigned short*)(w + 7077888);    // 1,179,648
  float*          gv     = (float*)(w + 8257536);             //   798,720
  float*          mf     = (float*)(w + 9056256);             //   393,216
  float*          mg     = (float*)(w + 9449472);             //   393,216
  float*          cntw   = (float*)(w + 9842688);             //       512
  float*          comb   = (float*)(w + 9843200);             //   393,216
  short*          w2T    = (short*)(w + 10236416);            //   393,216
  short*          w2r    = (short*)(w + 10629632);            //   393,216
  short*          w1t    = (short*)(w + 11022848);            //    16,384
  short*          Gm     = (short*)(w + 11039232);            //   147,456
  float*          g1s    = (float*)(w + 11186688);            //       512
  float*          gscal  = (float*)(w + 11187200);            //       256
  short*          wqT    = (short*)(w + 11187456);            // 1,179,648
  short*          wkT    = (short*)(w + 12367104);            // 1,179,648
  short*          wvT    = (short*)(w + 13546752);            // 1,179,648
  short*          woT    = (short*)(w + 14726400);            // 1,179,648
  unsigned short* ow_bf  = geo_bf;

  hipLaunchKernelGGL(k_prep,    dim3(2973),  dim3(256), 0, stream,
                     ge_w2, ge_w1, wq, wk, wv, wo,
                     gv, w2T, w2r, wqT, wkT, wvT, woT, w1t);
  hipLaunchKernelGGL(k_gprep,   dim3(258),   dim3(256), 0, stream,
                     w2T, ge_b2, w1t, ge_b1, Gm, gscal, g1s);
  hipLaunchKernelGGL(k_geo,     dim3(4608),  dim3(256), 0, stream,
                     coord, w1t, ge_b1, ge_g1, ge_be1, Gm, gscal, g1s, gv);
  hipLaunchKernelGGL(k_geofin,  dim3(768),   dim3(256), 0, stream,
                     gv, w2r, ge_b2, ge_g2, ge_be2, geo_bf);
  hipLaunchKernelGGL(k_scat,    dim3(768),   dim3(256), 0, stream,
                     lab, feat, geo_bf, mf, mg, cntw);
  hipLaunchKernelGGL(k_agg,     dim3(128),   dim3(256), 0, stream,
                     mf, mg, cntw, ag_w1, ag_b1, ag_g1, ag_be1, ag_w2, ag_b2, ag_g2, ag_be2, comb);
  hipLaunchKernelGGL(k_enhance, dim3(2304),  dim3(256), 0, stream,
                     feat, lab, cntw, comb, enh_f, enh_bf);
  hipLaunchKernelGGL(k_qkv,     dim3(216),   dim3(256), 0, stream,
                     enh_bf, geo_bf, wqT, wkT, wvT, bq, bk, bv, qw_bf, kw_bf, vw_bf);
  hipLaunchKernelGGL(k_attn,    dim3(192),   dim3(256), 0, stream,
                     qw_bf, kw_bf, vw_bf, ow_bf);
  hipLaunchKernelGGL(k_out,     dim3(72),    dim3(256), 0, stream,
                     ow_bf, enh_f, woT, bo, (float*)d_out);
}